// Round 1
// baseline (333.535 us; speedup 1.0000x reference)
//
#include <hip/hip_runtime.h>

// Each row = 64 float32 (0.0f / 1.0f) = bits of one fp64, element 0 is bit 63 (sign).
// out = bits of floor(|v| + 0.5) with original sign bit restored in slot 0.
__global__ __launch_bounds__(256) void SpikeFP64Round_kernel(
    const uint4* __restrict__ in, uint4* __restrict__ out, int nrows) {
    int row = blockIdx.x * blockDim.x + threadIdx.x;
    if (row >= nrows) return;

    const uint4* p = in + (size_t)row * 16;  // 16 uint4 = 64 floats = 256 B
    uint64_t u = 0;
    #pragma unroll
    for (int k = 0; k < 16; ++k) {
        uint4 q = p[k];
        // float is exactly 0.0f (0x00000000) or 1.0f (0x3F800000); bit 23 distinguishes.
        uint32_t nib = (((q.x >> 23) & 1u) << 3) |
                       (((q.y >> 23) & 1u) << 2) |
                       (((q.z >> 23) & 1u) << 1) |
                       (((q.w >> 23) & 1u));
        u = (u << 4) | (uint64_t)nib;   // element 0 ends up at bit 63
    }

    uint64_t sign = u & 0x8000000000000000ull;
    double v = __longlong_as_double((long long)(u & 0x7FFFFFFFFFFFFFFFull));
    double r = floor(v + 0.5);          // IEEE fp64 add + floor, bit-exact vs numpy
    uint64_t rb = (uint64_t)__double_as_longlong(r) | sign;  // r >= +0, bit63 was 0

    uint4* o = out + (size_t)row * 16;
    #pragma unroll
    for (int k = 0; k < 16; ++k) {
        uint4 q;
        q.x = ((rb >> (63 - 4 * k)) & 1ull) ? 0x3F800000u : 0u;
        q.y = ((rb >> (62 - 4 * k)) & 1ull) ? 0x3F800000u : 0u;
        q.z = ((rb >> (61 - 4 * k)) & 1ull) ? 0x3F800000u : 0u;
        q.w = ((rb >> (60 - 4 * k)) & 1ull) ? 0x3F800000u : 0u;
        o[k] = q;
    }
}

extern "C" void kernel_launch(void* const* d_in, const int* in_sizes, int n_in,
                              void* d_out, int out_size, void* d_ws, size_t ws_size,
                              hipStream_t stream) {
    (void)n_in; (void)d_ws; (void)ws_size; (void)out_size;
    const uint4* in = (const uint4*)d_in[0];
    uint4* out = (uint4*)d_out;
    int nrows = in_sizes[0] / 64;
    int block = 256;
    int grid = (nrows + block - 1) / block;
    SpikeFP64Round_kernel<<<grid, block, 0, stream>>>(in, out, nrows);
}

// Round 2
// 177.952 us; speedup vs baseline: 1.8743x; 1.8743x over previous
//
#include <hip/hip_runtime.h>

// Each row = 64 float32 (exactly 0.0f/1.0f) = bits of one fp64, element 0 = bit 63.
// out = bits of floor(|v| + 0.5) with original sign bit restored.
//
// Layout: one thread per 16B chunk (4 floats = 4 bits). 16 consecutive lanes own
// one row -> every global load/store instruction is wave-contiguous (1 KiB/instr).
// The 64-bit word is assembled across the 16-lane group via 4 butterfly OR-shuffles.
__global__ __launch_bounds__(256) void SpikeFP64Round_kernel(
    const uint4* __restrict__ in, uint4* __restrict__ out, long long nchunks) {
    long long idx = (long long)blockIdx.x * blockDim.x + threadIdx.x;
    if (idx >= nchunks) return;

    uint4 q = in[idx];  // coalesced: lane i -> 16B at idx*16

    int sub = threadIdx.x & 15;           // chunk position within the row
    // float is exactly 0.0f (0x00000000) or 1.0f (0x3F800000); bit 23 distinguishes.
    uint32_t nib = (((q.x >> 23) & 1u) << 3) |
                   (((q.y >> 23) & 1u) << 2) |
                   (((q.z >> 23) & 1u) << 1) |
                   (((q.w >> 23) & 1u));
    int sh = 60 - 4 * sub;                // this chunk's bits sit at [sh+3 : sh]
    uint64_t part = (uint64_t)nib << sh;

    // Butterfly OR across the 16-lane group (masks 1,2,4,8 stay within the group).
    uint32_t lo = (uint32_t)part;
    uint32_t hi = (uint32_t)(part >> 32);
    #pragma unroll
    for (int m = 1; m <= 8; m <<= 1) {
        lo |= __shfl_xor(lo, m);
        hi |= __shfl_xor(hi, m);
    }
    uint64_t u = ((uint64_t)hi << 32) | lo;

    uint64_t sign = u & 0x8000000000000000ull;
    double v = __longlong_as_double((long long)(u & 0x7FFFFFFFFFFFFFFFull));
    double r = floor(v + 0.5);            // IEEE fp64 add + floor, bit-exact vs numpy
    uint64_t rb = (uint64_t)__double_as_longlong(r) | sign;

    uint4 o;
    o.x = ((rb >> (sh + 3)) & 1ull) ? 0x3F800000u : 0u;
    o.y = ((rb >> (sh + 2)) & 1ull) ? 0x3F800000u : 0u;
    o.z = ((rb >> (sh + 1)) & 1ull) ? 0x3F800000u : 0u;
    o.w = ((rb >> (sh + 0)) & 1ull) ? 0x3F800000u : 0u;
    out[idx] = o;                         // coalesced store
}

extern "C" void kernel_launch(void* const* d_in, const int* in_sizes, int n_in,
                              void* d_out, int out_size, void* d_ws, size_t ws_size,
                              hipStream_t stream) {
    (void)n_in; (void)d_ws; (void)ws_size; (void)out_size;
    const uint4* in = (const uint4*)d_in[0];
    uint4* out = (uint4*)d_out;
    long long nchunks = (long long)in_sizes[0] / 4;   // 4 floats per uint4 chunk
    int block = 256;
    long long grid = (nchunks + block - 1) / block;
    SpikeFP64Round_kernel<<<(int)grid, block, 0, stream>>>(in, out, nchunks);
}